// Round 11
// baseline (300.358 us; speedup 1.0000x reference)
//
#include <hip/hip_runtime.h>

typedef __bf16 bf16;
typedef __attribute__((ext_vector_type(8))) __bf16 bf16x8;
typedef __attribute__((ext_vector_type(4))) __bf16 bf16x4;
typedef __attribute__((ext_vector_type(4))) float f32x4;
typedef __attribute__((ext_vector_type(4))) short short4v;

// ---- constants for this problem ----
#define BB 2
#define TT 2048
#define DD 2048
#define HH 16
#define HKV 4
#define DHD 128
#define NQKV 3072   // H*DH + 2*HKV*DH

__device__ __forceinline__ void gl_lds16(const bf16* g, bf16* l) {
    __builtin_amdgcn_global_load_lds(
        (const __attribute__((address_space(1))) void*)g,
        (__attribute__((address_space(3))) void*)l, 16, 0, 0);
}

// ---------------- fused fp32->bf16 converts + gates (frozen R11) ----------------
__global__ void cvt_fuse(const float* __restrict__ x, const float* __restrict__ Wq,
                         const float* __restrict__ Wk, const float* __restrict__ Wv,
                         const float* __restrict__ Wo, const float* __restrict__ gw,
                         bf16* __restrict__ xb, bf16* __restrict__ wqkvb,
                         bf16* __restrict__ wob, float* __restrict__ gates) {
    const int blk = blockIdx.x, tid = threadIdx.x;
    const float* src; bf16* dst; int i;
    const bool isx = blk < 4096;
    if (isx)              { src = x;  dst = xb;              i = blk * 256 + tid; }
    else if (blk < 6144)  { src = Wq; dst = wqkvb;           i = (blk - 4096) * 256 + tid; }
    else if (blk < 6656)  { src = Wk; dst = wqkvb + 4194304; i = (blk - 6144) * 256 + tid; }
    else if (blk < 7168)  { src = Wv; dst = wqkvb + 5242880; i = (blk - 6656) * 256 + tid; }
    else                  { src = Wo; dst = wob;             i = (blk - 7168) * 256 + tid; }
    float4 a = ((const float4*)src)[i * 2];
    float4 b = ((const float4*)src)[i * 2 + 1];
    bf16x8 v;
    v[0] = (bf16)a.x; v[1] = (bf16)a.y; v[2] = (bf16)a.z; v[3] = (bf16)a.w;
    v[4] = (bf16)b.x; v[5] = (bf16)b.y; v[6] = (bf16)b.z; v[7] = (bf16)b.w;
    *(bf16x8*)(dst + (size_t)i * 8) = v;

    if (isx) {
        __shared__ float xs16[16];
        __shared__ float gws[256];
        gws[tid] = gw[tid];
        if (tid < 2) {
            xs16[tid * 8 + 0] = a.x; xs16[tid * 8 + 1] = a.y;
            xs16[tid * 8 + 2] = a.z; xs16[tid * 8 + 3] = a.w;
            xs16[tid * 8 + 4] = b.x; xs16[tid * 8 + 5] = b.y;
            xs16[tid * 8 + 6] = b.z; xs16[tid * 8 + 7] = b.w;
        }
        __syncthreads();
        if (tid < 16) {
            float z = 0.f;
#pragma unroll
            for (int j = 0; j < 16; j++) z += xs16[j] * gws[tid * 16 + j];
            gates[blk * 16 + tid] = 1.f / (1.f + __expf(-z));
        }
    }
}

// ---------------- QKV GEMM: 256x256 tile, K-subtile-32 ring, counted vmcnt ----------------
// R15 (resubmitted after R10 infra failure; invariants re-audited):
// Ring As/Bs[4 slots][256 rows][32 k], slot = subtile&3, 128 KiB LDS, 512 thr
// (2M x 4N waves, 128x64/wave). Per iter j: vmcnt(4) [subtile j+1 landed];
// s_barrier [orders all waves' slot-(j-1) read-drain before any stage below];
// lgkm(0)+sched_barrier [frags(j) ready, rule #18]; stage(j+3)->slot (j-1)&3
// [WAR-safe by the barrier]; 32 MFMA on frags(j); read-ahead frags(j+1)
// [RAW-safe by vmcnt]. Loads never drain to 0. T2 swizzle: stage chunk
// (lane&3)^((lane>>3)&3), read slot quad^((l15>>1)&3) (verified algebra).
// T1 bijective XCD swizzle (192%8==0). Fused epilogue = R9-verified 2-head
// version, run as two 128-row passes.
__global__ __launch_bounds__(512, 2)
void gemm_qkv256(const bf16* __restrict__ A, const bf16* __restrict__ Bw,
                 bf16* __restrict__ qb, bf16* __restrict__ kb,
                 bf16* __restrict__ vtb,
                 const float* __restrict__ v1,
                 const float* __restrict__ cosb,
                 const float* __restrict__ sinb,
                 const float* __restrict__ lamp) {
    __shared__ bf16 smem[65536];          // 128 KiB
    bf16* As = smem;                      // [4][256*32]
    bf16* Bs = smem + 32768;
    const int tid = threadIdx.x;
    const int w = tid >> 6, lane = tid & 63;
    const int l15 = lane & 15, quad = lane >> 4;
    const int wr = w >> 2, wc = w & 3;    // 2M x 4N

    const int nwg = gridDim.x * gridDim.y;            // 192
    int wg = blockIdx.y * gridDim.x + blockIdx.x;
    int swz = (wg & 7) * (nwg >> 3) + (wg >> 3);
    const int bx = swz % gridDim.x, by = swz / gridDim.x;
    const int m0 = by * 256, n0 = bx * 256;

    const int srow = lane >> 2;                               // 0..15
    const int sck = ((lane & 3) ^ ((lane >> 3) & 3)) * 8;     // stage source swizzle
    const int xs = (quad ^ ((l15 >> 1) & 3)) * 8;             // read swizzle

    auto stage = [&](int j) {             // stage k-subtile j (clamped) into slot j&3
        int jc = j > 63 ? 63 : j;
        int slot = j & 3;
        size_t kk = (size_t)(jc << 5) + sck;
#pragma unroll
        for (int i = 0; i < 2; i++) {
            int row = w * 32 + i * 16 + srow;
            gl_lds16(A + (size_t)(m0 + row) * 2048 + kk,
                     As + slot * 8192 + w * 1024 + i * 512);
            gl_lds16(Bw + (size_t)(n0 + row) * 2048 + kk,
                     Bs + slot * 8192 + w * 1024 + i * 512);
        }
    };

    f32x4 acc[8][4] = {};
    bf16x8 af[8], bfv[4];

    auto rdfrags = [&](int j) {
        int slot = j & 3;
        const bf16* Ab = As + slot * 8192 + (wr * 128) * 32;
        const bf16* Bb = Bs + slot * 8192 + (wc * 64) * 32;
#pragma unroll
        for (int mi = 0; mi < 8; mi++)
            af[mi] = *(const bf16x8*)(Ab + (mi * 16 + l15) * 32 + xs);
#pragma unroll
        for (int ni = 0; ni < 4; ni++)
            bfv[ni] = *(const bf16x8*)(Bb + (ni * 16 + l15) * 32 + xs);
    };

    // prologue: subtiles 0,1,2 staged; frags(0) read
    stage(0); stage(1); stage(2);
    asm volatile("s_waitcnt vmcnt(8)" ::: "memory");   // subtile 0 landed
    __builtin_amdgcn_s_barrier();
    asm volatile("" ::: "memory");
    rdfrags(0);

    for (int j = 0; j < 64; j++) {
        asm volatile("s_waitcnt vmcnt(4)" ::: "memory");   // subtile j+1 landed
        __builtin_amdgcn_s_barrier();
        asm volatile("" ::: "memory");
        asm volatile("s_waitcnt lgkmcnt(0)" ::: "memory"); // frags(j) in regs
        __builtin_amdgcn_sched_barrier(0);                 // rule #18
        stage(j + 3);                                      // slot (j-1)&3, WAR-safe
        __builtin_amdgcn_s_setprio(1);
#pragma unroll
        for (int mi = 0; mi < 8; mi++)
#pragma unroll
            for (int ni = 0; ni < 4; ni++)
                acc[mi][ni] = __builtin_amdgcn_mfma_f32_16x16x32_bf16(af[mi], bfv[ni], acc[mi][ni], 0, 0, 0);
        __builtin_amdgcn_s_setprio(0);
        rdfrags(j + 1);                                    // for next iter
    }
    __syncthreads();   // drain tail stages; LDS reused by epilogue

    // ---- fused epilogue: 2 heads (hp2, hp2+1), two 128-row passes ----
    const int hp2 = n0 >> 7;          // even head base: 0..14 q, 16/18 k, 20/22 v
    const int b = m0 >> 11;
    const int t0 = m0 & (TT - 1);
    bf16* ep = smem;                  // [2 heads][128][136] = 69632 B
    float* ssum = (float*)((char*)smem + 69632);   // [4 wc][128]

    const float QSCALE = 0.08838834764831845f * 1.4426950408889634f;
    float lam = (hp2 >= 20) ? lamp[0] : 0.f;

#pragma unroll
    for (int rh = 0; rh < 2; rh++) {
        if (hp2 < 20) {
            if (wr == rh) {
#pragma unroll
                for (int mi = 0; mi < 8; mi++)
#pragma unroll
                    for (int r = 0; r < 4; r++) {
                        float s = 0.f;
#pragma unroll
                        for (int ni = 0; ni < 4; ni++) {
                            float vv = acc[mi][ni][r];
                            s += vv * vv;
                        }
                        s += __shfl_xor(s, 1);
                        s += __shfl_xor(s, 2);
                        s += __shfl_xor(s, 4);
                        s += __shfl_xor(s, 8);
                        if (l15 == 0) ssum[wc * 128 + mi * 16 + quad * 4 + r] = s;
                    }
            }
            __syncthreads();
            if (wr == rh) {
#pragma unroll
                for (int mi = 0; mi < 8; mi++) {
                    float rn[4];
#pragma unroll
                    for (int r = 0; r < 4; r++) {
                        int row = mi * 16 + quad * 4 + r;
                        float ss = ssum[(wc & ~1) * 128 + row] + ssum[((wc & ~1) | 1) * 128 + row];
                        float rv = rsqrtf(ss * (1.f / 128.f) + 1e-6f);
                        if (hp2 < HH) rv *= QSCALE;
                        rn[r] = rv;
                    }
#pragma unroll
                    for (int ni = 0; ni < 4; ni++)
#pragma unroll
                        for (int r = 0; r < 4; r++) {
                            float sv = acc[mi][ni][r] * rn[r];
                            float pv = __shfl_xor(sv, 1);
                            int nl = (wc & 1) * 64 + ni * 16 + l15;
                            int jj = nl >> 1;
                            int tl = mi * 16 + quad * 4 + r;
                            float c = cosb[(size_t)(t0 + rh * 128 + tl) * 64 + jj];
                            float s = sinb[(size_t)(t0 + rh * 128 + tl) * 64 + jj];
                            float o = (nl & 1) ? (sv * c + pv * s) : (sv * c - pv * s);
                            int oc = (nl & 1) ? (64 + jj) : jj;
                            ep[(wc >> 1) * 17408 + tl * 136 + oc] = (bf16)o;
                        }
                }
            }
            __syncthreads();
            int tl = tid >> 2, sg = tid & 3;
#pragma unroll
            for (int hd = 0; hd < 2; hd++) {
                int hg = hp2 + hd;
                bf16* dst = (hp2 < HH)
                    ? (qb + ((size_t)(b * HH + hg) * TT + t0 + rh * 128) * DHD)
                    : (kb + ((size_t)(b * HKV + (hg - HH)) * TT + t0 + rh * 128) * DHD);
#pragma unroll
                for (int c8 = 0; c8 < 4; c8++)
                    *(bf16x8*)(dst + (size_t)tl * DHD + sg * 8 + c8 * 32) =
                        *(const bf16x8*)(ep + hd * 17408 + tl * 136 + sg * 8 + c8 * 32);
            }
            __syncthreads();
        } else {
            if (wr == rh) {
#pragma unroll
                for (int mi = 0; mi < 8; mi++)
#pragma unroll
                    for (int ni = 0; ni < 4; ni++)
#pragma unroll
                        for (int r = 0; r < 4; r++) {
                            int d = (wc & 1) * 64 + ni * 16 + l15;
                            int tl = mi * 16 + quad * 4 + r;
                            int vh = hp2 - 20 + (wc >> 1);
                            float val = acc[mi][ni][r];
                            float vm = val + lam * (v1[((size_t)(b * HKV + vh) * TT + t0 + rh * 128 + tl) * DHD + d] - val);
                            ep[(wc >> 1) * 17408 + d * 136 + tl] = (bf16)vm;
                        }
            }
            __syncthreads();
            int dd = tid >> 2, sg = tid & 3;
#pragma unroll
            for (int hd = 0; hd < 2; hd++) {
                int vh = hp2 - 20 + hd;
                bf16* dstv = vtb + ((size_t)(b * HKV + vh) * DHD + dd) * TT + t0 + rh * 128;
#pragma unroll
                for (int c8 = 0; c8 < 4; c8++)
                    *(bf16x8*)(dstv + sg * 8 + c8 * 32) =
                        *(const bf16x8*)(ep + hd * 17408 + dd * 136 + sg * 8 + c8 * 32);
            }
            __syncthreads();
        }
    }
}

// ---------------- GEMM (MODE 0 only now): R10 structure, frozen ----------------
template <int MODE>
__global__ void gemm_bt(const bf16* __restrict__ A, const bf16* __restrict__ Bw,
                        int M, int N, int K,
                        float* __restrict__ Cout) {
    __shared__ bf16 smem[16384];
    bf16* As = smem;
    bf16* Bs = smem + 8192;
    const int tid = threadIdx.x;
    const int w = tid >> 6, lane = tid & 63;
    const int l15 = lane & 15, quad = lane >> 4;

    const int nwg = gridDim.x * gridDim.y;
    int wg = blockIdx.y * gridDim.x + blockIdx.x;
    int swz = (wg & 7) * (nwg >> 3) + (wg >> 3);
    const int bx = swz % gridDim.x, by = swz / gridDim.x;
    const int m0 = by * 128, n0 = bx * 128;
    const int wm = (w & 1) * 64, wn = (w >> 1) * 64;

    f32x4 acc[4][4] = {};
    const int lrow = lane >> 2;
    const int scol = ((lane & 3) ^ ((lane >> 3) & 3)) * 8;
    const int xs = (quad ^ ((l15 >> 1) & 3)) * 8;

    for (int k0 = 0; k0 < K; k0 += 64) {
#pragma unroll
        for (int i = 0; i < 4; i++) {
            int c = w * 4 + i;
            int kc2 = c >> 3, rc = c & 7;
            int row = rc * 16 + lrow;
            int kk = k0 + kc2 * 32 + scol;
            gl_lds16(A + (size_t)(m0 + row) * K + kk, As + c * 512);
            gl_lds16(Bw + (size_t)(n0 + row) * K + kk, Bs + c * 512);
        }
        __syncthreads();
#pragma unroll
        for (int kc2 = 0; kc2 < 2; kc2++) {
            bf16x8 af[4], bfr[4];
#pragma unroll
            for (int mi = 0; mi < 4; mi++)
                af[mi] = *(const bf16x8*)(As + kc2 * 4096 + ((wm >> 4) + mi) * 512 + l15 * 32 + xs);
#pragma unroll
            for (int ni = 0; ni < 4; ni++)
                bfr[ni] = *(const bf16x8*)(Bs + kc2 * 4096 + ((wn >> 4) + ni) * 512 + l15 * 32 + xs);
#pragma unroll
            for (int mi = 0; mi < 4; mi++)
#pragma unroll
                for (int ni = 0; ni < 4; ni++)
                    acc[mi][ni] = __builtin_amdgcn_mfma_f32_16x16x32_bf16(af[mi], bfr[ni], acc[mi][ni], 0, 0, 0);
        }
        __syncthreads();
    }

#pragma unroll
    for (int mi = 0; mi < 4; mi++)
#pragma unroll
        for (int ni = 0; ni < 4; ni++)
#pragma unroll
            for (int r = 0; r < 4; r++) {
                int m = m0 + wm + mi * 16 + quad * 4 + r;
                int n = n0 + wn + ni * 16 + l15;
                Cout[(size_t)m * N + n] = acc[mi][ni][r];
            }
}

// ---------------- flash attention (frozen R14) ----------------
__global__ __launch_bounds__(256, 2) void fattn(const bf16* __restrict__ qbuf,
                                                const bf16* __restrict__ kbuf,
                                                const bf16* __restrict__ vt,
                                                const float* __restrict__ gates,
                                                bf16* __restrict__ yb,
                                                const float* __restrict__ v1f,
                                                float* __restrict__ vout) {
    __shared__ bf16 Ks[2][8192];
    __shared__ bf16 VTs[2][8192];

    const int bid = blockIdx.x;
    const int bh = bid & 31;
    const int gg = bid >> 5;
    const int g = gg & 7, qhalf = gg >> 3;
    const int h = bh & 15, b = bh >> 4;
    const int hk = h >> 2;
    const int tid = threadIdx.x, wq = tid >> 6, lane = tid & 63;
    const int l15 = lane & 15, quad = lane >> 4;

    {
        const float4* s4 = (const float4*)(v1f + (size_t)bid * 4096);
        float4* d4 = (float4*)(vout + (size_t)bid * 4096);
#pragma unroll
        for (int i = 0; i < 4; i++) d4[tid + i * 256] = s4[tid + i * 256];
    }

    const bf16* qbase = qbuf + ((size_t)(b * HH + h) * TT) * DHD;
    const bf16* kbase = kbuf + ((size_t)(b * HKV + hk) * TT) * DHD;
    const bf16* vtbase = vt + ((size_t)(b * HKV + hk) * DHD) * TT;

    const int Tq0 = qhalf ? (15 - g) : g;
    const int Tq1 = qhalf ? (16 + g) : (31 - g);
    const int ktmax_blk = Tq1;

    bf16x8 qf0[4], qf1[4];
#pragma unroll
    for (int kc = 0; kc < 4; kc++) {
        qf0[kc] = *(const bf16x8*)(qbase + (size_t)(Tq0 * 64 + wq * 16 + l15) * DHD + kc * 32 + quad * 8);
        qf1[kc] = *(const bf16x8*)(qbase + (size_t)(Tq1 * 64 + wq * 16 + l15) * DHD + kc * 32 + quad * 8);
    }

    bool dm[4][4];
#pragma unroll
    for (int ni = 0; ni < 4; ni++)
#pragma unroll
        for (int r = 0; r < 4; r++)
            dm[ni][r] = ((ni >> 1) * 32 + quad * 8 + (ni & 1) * 4 + r) > (wq * 16 + l15);

    const int srow = lane >> 2;
    const int gst = (((lane >> 5) & 1) << 1) | ((lane >> 3) & 1);
    const int scg = ((lane & 3) ^ gst) * 8;
    const int vrow = lane >> 3;
    const int vcg = ((lane & 7) ^ ((lane >> 3) & 7)) * 8;

    auto stage = [&](int kt, int buf) {
#pragma unroll
        for (int i = 0; i < 4; i++)
            gl_lds16(kbase + (size_t)(kt * 64 + wq * 16 + srow) * DHD + i * 32 + scg,
                     &Ks[buf][i * 2048 + wq * 512]);
#pragma unroll
        for (int i = 0; i < 4; i++)
            gl_lds16(vtbase + (size_t)(wq * 32 + i * 8 + vrow) * TT + kt * 64 + vcg,
                     &VTs[buf][wq * 2048 + i * 512]);
    };

    stage(0, 0);

    const int gk = (((l15 >> 2) & 1) << 1) | ((l15 >> 1) & 1);

    f32x4 O0[8] = {}, O1[8] = {};
    float m0 = -INFINITY, l0 = 0.f, m1 = -INFINITY, l1 = 0.f;

    union PW { bf16x4 h[2]; bf16x8 v; };

    for (int kt = 0; kt <= ktmax_blk; kt++) {
        int cur = kt & 1;
        __syncthreads();
        if (kt < ktmax_blk) stage(kt + 1, cur ^ 1);

        const bool a0 = (kt <= Tq0);

        f32x4 s0[4], s1[4];
        __builtin_amdgcn_s_setprio(1);
#pragma unroll
        for (int ni = 0; ni < 4; ni++) {
            int rr = (ni >> 1) * 32 + (l15 >> 2) * 8 + (ni & 1) * 4 + (l15 & 3);
            bf16x8 kfl[4];
#pragma unroll
            for (int kc = 0; kc < 4; kc++)
                kfl[kc] = *(const bf16x8*)(&Ks[cur][kc * 2048 + rr * 32 + ((quad ^ gk) * 8)]);
            f32x4 z1 = {};
#pragma unroll
            for (int kc = 0; kc < 4; kc++)
                z1 = __builtin_amdgcn_mfma_f32_16x16x32_bf16(kfl[kc], qf1[kc], z1, 0, 0, 0);
            s1[ni] = z1;
            if (a0) {
                f32x4 z0 = {};
#pragma unroll
                for (int kc = 0; kc < 4; kc++)
                    z0 = __builtin_amdgcn_mfma_f32_16x16x32_bf16(kfl[kc], qf0[kc], z0, 0, 0, 0);
                s0[ni] = z0;
            }
        }
        __builtin_amdgcn_s_setprio(0);

        PW pw0[2], pw1[2];
        {
            if (kt == Tq1) {
#pragma unroll
                for (int ni = 0; ni < 4; ni++)
#pragma unroll
                    for (int r = 0; r < 4; r++)
                        if (dm[ni][r]) s1[ni][r] = -INFINITY;
            }
            float mx = s1[0][0];
#pragma unroll
            for (int ni = 0; ni < 4; ni++)
#pragma unroll
                for (int r = 0; r < 4; r++) mx = fmaxf(mx, s1[ni][r]);
            mx = fmaxf(mx, __shfl_xor(mx, 16));
            mx = fmaxf(mx, __shfl_xor(mx, 32));
            float mold = m1;
            bool noresc = __all(mx <= mold + 8.f);
            float mnew = noresc ? mold : fmaxf(mold, mx);
            float rs = 0.f;
#pragma unroll
            for (int ni = 0; ni < 4; ni++) {
                bf16x4 hv;
#pragma unroll
                for (int r = 0; r < 4; r++) {
                    float pe = __builtin_amdgcn_exp2f(s1[ni][r] - mnew);
                    hv[r] = (bf16)pe;
                    rs += pe;
                }
                pw1[ni >> 1].h[ni & 1] = hv;
            }
            rs += __shfl_xor(rs, 16);
            rs += __shfl_xor(rs, 32);
            if (!noresc) {
                float al = __builtin_amdgcn_exp2f(mold - mnew);
                l1 *= al;
#pragma unroll
                for (int dn = 0; dn < 8; dn++)
#pragma unroll
                    for (int r = 0; r < 4; r++) O1[dn][r] *= al;
                m1 = mnew;
            }
            l1 += rs;
        }
        if (a0) {
            if (kt == Tq0) {
#pragma unroll
                for (int ni = 0; ni < 4; ni++)
#pragma unroll
                    for (int r = 0; r < 4; r++)
                        if (dm[ni][r]) s0[ni][r] = -INFINITY;
            }
            float mx = s0[0][0];
#pragma unroll
            for (int ni = 0; ni < 4; ni++)
#pragma unroll
                for (int r = 0; r < 4; r++) mx = fmaxf(mx, s0[ni][r]);
            mx = fmaxf(mx, __shfl_xor(mx, 16));
            mx = fmaxf(mx, __shfl_xor(mx, 32));
            float mold = m0;
            bool noresc = __all(mx <= mold + 8.f);
            float mnew = noresc ? mold : fmaxf(mold, mx);
            float rs = 0.f;
#pragma unroll
            for (int ni = 0; ni < 4; ni++) {
                bf16x4 hv;
#pragma unroll
                for (int r = 0; r < 4; r++) {
                    float pe = __builtin_amdgcn_exp2f(s0[ni][r] - mnew);
                    hv[r] = (bf16)pe;
                    rs += pe;
                }
                pw0[ni >> 1].h[ni & 1] = hv;
            }
            rs += __shfl_xor(rs, 16);
            rs += __shfl_xor(rs, 32);
            if (!noresc) {
                float al = __builtin_amdgcn_exp2f(mold - mnew);
                l0 *= al;
#pragma unroll
                for (int dn = 0; dn < 8; dn++)
#pragma unroll
                    for (int r = 0; r < 4; r++) O0[dn][r] *= al;
                m0 = mnew;
            }
            l0 += rs;
        }

        __builtin_amdgcn_s_setprio(1);
#pragma unroll
        for (int ni2 = 0; ni2 < 2; ni2++) {
            bf16x8 vfl[8];
#pragma unroll
            for (int dn = 0; dn < 8; dn++)
                vfl[dn] = *(const bf16x8*)(&VTs[cur][(dn * 16 + l15) * 64 +
                                                    (((ni2 * 4 + quad) ^ (l15 & 7)) * 8)]);
#pragma unroll
            for (int dn = 0; dn < 8; dn++)
                O1[dn] = __builtin_amdgcn_mfma_f32_16x16x32_bf16(vfl[dn], pw1[ni2].v, O1[dn], 0, 0, 0);
            if (a0) {
#pragma unroll
                for (int dn = 0; dn < 8; dn++)
                    O0[dn] = __builtin_amdgcn_mfma_f32_16x16x32_bf16(vfl[dn], pw0[ni2].v, O0[dn], 0, 0, 0);
            }
        }
        __builtin_amdgcn_s_setprio(0);
    }

    auto epi = [&](const f32x4* Oc, float lsum, int qt) {
        int qg = qt * 64 + wq * 16 + l15;
        float gi = gates[((size_t)b * TT + qg) * HH + h] / lsum;
#pragma unroll
        for (int dn = 0; dn < 8; dn++) {
            bf16x4 o;
#pragma unroll
            for (int r = 0; r < 4; r++) o[r] = (bf16)(Oc[dn][r] * gi);
            *(bf16x4*)(yb + ((size_t)(b * TT + qg) * HH + h) * DHD + dn * 16 + quad * 4) = o;
        }
    };
    epi(O0, l0, Tq0);
    epi(O1, l1, Tq1);
}

extern "C" void kernel_launch(void* const* d_in, const int* in_sizes, int n_in,
                              void* d_out, int out_size, void* d_ws, size_t ws_size,
                              hipStream_t stream) {
    const float* x    = (const float*)d_in[0];
    const float* cosb = (const float*)d_in[2];
    const float* sinb = (const float*)d_in[3];
    const float* v1   = (const float*)d_in[4];
    const float* Wq   = (const float*)d_in[5];
    const float* Wk   = (const float*)d_in[6];
    const float* Wv   = (const float*)d_in[7];
    const float* Wo   = (const float*)d_in[8];
    const float* gw   = (const float*)d_in[9];
    const float* lam  = (const float*)d_in[10];
    float* out = (float*)d_out;

    char* ws = (char*)d_ws;
    bf16* xb     = (bf16*)(ws);                   // 16,777,216 B (reused later by yb)
    bf16* wqkvb  = (bf16*)(ws + 16777216);        // 12,582,912
    bf16* wob    = (bf16*)(ws + 29360128);        //  8,388,608
    bf16* qb     = (bf16*)(ws + 79691776);        // 16,777,216
    bf16* kb     = (bf16*)(ws + 96468992);        //  4,194,304
    bf16* vtb    = (bf16*)(ws + 100663296);       //  4,194,304
    float* gts   = (float*)(ws + 104857600);      //    262,144
    bf16* yb     = xb;                            // alias: xb dead after QKV GEMM

    // all converts + gates in ONE launch
    cvt_fuse<<<9216, 256, 0, stream>>>(x, Wq, Wk, Wv, Wo, gw, xb, wqkvb, wob, gts);

    // QKV projection + fused rmsnorm/rope/v-mix epilogues (256^2 ring schedule)
    gemm_qkv256<<<dim3(12, 16), 512, 0, stream>>>(xb, wqkvb, qb, kb, vtb, v1,
                                                  cosb, sinb, lam);
    // flash attention -- yb aliases xb; also copies v1 -> out[8388608..]
    fattn<<<512, 256, 0, stream>>>(qb, kb, vtb, gts, yb, v1, out + 8388608);
    // output projection
    gemm_bt<0><<<dim3(16, 32), 256, 0, stream>>>(yb, wob, 4096, 2048, 2048, out);
}